// Round 1
// 245.900 us; speedup vs baseline: 1.0814x; 1.0814x over previous
//
#include <hip/hip_runtime.h>
#include <stdint.h>

// MHA: B=2, S=2048, D=1024, H=16, DK=64.
// Inputs fp32, mask int32, output fp32 (bf16-grade tolerance).
// Internal: bf16 (pre-converted X, pre-transposed W).
typedef unsigned short u16;
typedef __bf16 bf16x8 __attribute__((ext_vector_type(8), may_alias));
typedef unsigned short u16x8 __attribute__((ext_vector_type(8), may_alias));
typedef unsigned short u16x4 __attribute__((ext_vector_type(4), may_alias));
typedef float f32x4 __attribute__((ext_vector_type(4)));
typedef float f32x16 __attribute__((ext_vector_type(16)));

__device__ __forceinline__ u16 f2bf(float f) {
    union { float f; uint32_t i; } v; v.f = f;
    return (u16)((v.i + 0x7FFFu + ((v.i >> 16) & 1u)) >> 16);
}

__device__ __forceinline__ float exp2_hw(float x) {
#if __has_builtin(__builtin_amdgcn_exp2f)
    return __builtin_amdgcn_exp2f(x);
#else
    float r; asm("v_exp_f32 %0, %1" : "=v"(r) : "v"(x)); return r;
#endif
}

__device__ __forceinline__ uint32_t cvt_pk_bf16(float a, float b) {
    uint32_t r;
    asm("v_cvt_pk_bf16_f32 %0, %1, %2" : "=v"(r) : "v"(a), "v"(b));
    return r;
}

// async 16B global -> LDS (wave-uniform LDS base + lane*16; m97 pattern)
__device__ __forceinline__ void gld_lds16(const u16* g, u16* l) {
    __builtin_amdgcn_global_load_lds(
        (const __attribute__((address_space(1))) unsigned int*)g,
        (__attribute__((address_space(3))) unsigned int*)l, 16, 0, 0);
}

// ---------------------------------------------------------------------------
// cvt_all: z<3 -> X fp32->bf16 copy (1024 blocks, 16 elem/thr);
//          z>=3 -> W fp32 [k][n] -> bf16 [n][k] transpose (256 blocks active).
// grid (1024, 1, 7).
// ---------------------------------------------------------------------------
__global__ __launch_bounds__(256) void cvt_all(
    const float* __restrict__ s0, const float* __restrict__ s1, const float* __restrict__ s2,
    const float* __restrict__ w0, const float* __restrict__ w1,
    const float* __restrict__ w2, const float* __restrict__ w3,
    u16* __restrict__ d0, u16* __restrict__ d1, u16* __restrict__ d2,
    u16* __restrict__ t0, u16* __restrict__ t1,
    u16* __restrict__ t2, u16* __restrict__ t3)
{
    __shared__ float L[64][65];
    const int z = blockIdx.z;
    const int tid = threadIdx.x;
    if (z < 3) {
        const float* s = (z == 0) ? s0 : (z == 1) ? s1 : s2;
        u16*         d = (z == 0) ? d0 : (z == 1) ? d1 : d2;
        const size_t base = ((size_t)blockIdx.x * 256 + tid) * 16;
        #pragma unroll
        for (int p = 0; p < 2; ++p) {
            float4 a = *reinterpret_cast<const float4*>(s + base + p * 8);
            float4 b = *reinterpret_cast<const float4*>(s + base + p * 8 + 4);
            u16x8 o;
            o[0] = f2bf(a.x); o[1] = f2bf(a.y); o[2] = f2bf(a.z); o[3] = f2bf(a.w);
            o[4] = f2bf(b.x); o[5] = f2bf(b.y); o[6] = f2bf(b.z); o[7] = f2bf(b.w);
            *reinterpret_cast<u16x8*>(d + base + p * 8) = o;
        }
    } else {
        if (blockIdx.x >= 256) return;
        const int zi = z - 3;
        const float* w = (zi == 0) ? w0 : (zi == 1) ? w1 : (zi == 2) ? w2 : w3;
        u16*         t = (zi == 0) ? t0 : (zi == 1) ? t1 : (zi == 2) ? t2 : t3;
        const int k0 = (blockIdx.x & 15) * 64, n0 = (blockIdx.x >> 4) * 64;
        const int rr = tid >> 6, cc = tid & 63;
        #pragma unroll
        for (int p = 0; p < 16; ++p)
            L[p * 4 + rr][cc] = w[(size_t)(k0 + p * 4 + rr) * 1024 + n0 + cc];
        __syncthreads();
        #pragma unroll
        for (int p = 0; p < 16; ++p)
            t[(size_t)(n0 + p * 4 + rr) * 1024 + k0 + cc] = f2bf(L[cc][p * 4 + rr]);
    }
}

// ---------------------------------------------------------------------------
// m97-style GEMM: 128x128 tile, BK=32, global_load_lds width=16.
// grid (32, 8, Z).  NEW: mode-0 z==0 (Q projection) output is pre-scaled by
// 0.125*log2(e) so attention can use raw v_exp (exp2) with no per-element mul.
// ---------------------------------------------------------------------------
__global__ __launch_bounds__(256) void gemm_bt(
    const u16* __restrict__ A0, const u16* __restrict__ A1, const u16* __restrict__ A2,
    const u16* __restrict__ B0, const u16* __restrict__ B1, const u16* __restrict__ B2,
    const float* __restrict__ c0, const float* __restrict__ c1, const float* __restrict__ c2,
    void* __restrict__ d0, void* __restrict__ d1, void* __restrict__ d2,
    int mode_override)
{
    __shared__ u16 As[128 * 32];
    __shared__ u16 Bs[128 * 32];

    const int z = blockIdx.z;
    const u16* A = (z == 0) ? A0 : (z == 1) ? A1 : A2;
    const u16* BT = (z == 0) ? B0 : (z == 1) ? B1 : B2;
    const float* bias = (z == 0) ? c0 : (z == 1) ? c1 : c2;
    void* dst = (z == 0) ? d0 : (z == 1) ? d1 : d2;
    const int mode = (mode_override >= 0) ? mode_override : ((z == 2) ? 2 : 0);

    const int tid  = threadIdx.x;
    const int wave = tid >> 6, lane = tid & 63;
    const int quad = lane >> 4, l15 = lane & 15;
    const int row0 = blockIdx.x * 128, col0 = blockIdx.y * 128;
    const int wrow = (wave >> 1) * 64, wcol = (wave & 1) * 64;

    f32x4 acc[4][4] = {};

    for (int k0 = 0; k0 < 1024; k0 += 32) {
        __syncthreads();
        #pragma unroll
        for (int j = 0; j < 2; ++j) {
            const int idx = j * 256 + tid;
            const int r = idx >> 2, kc = (idx & 3) * 8;
            gld_lds16(A  + (size_t)(row0 + r) * 1024 + k0 + kc,
                      &As[(size_t)(j * 256 + wave * 64) * 8]);
            gld_lds16(BT + (size_t)(col0 + r) * 1024 + k0 + kc,
                      &Bs[(size_t)(j * 256 + wave * 64) * 8]);
        }
        __syncthreads();

        bf16x8 a[4], b[4];
        #pragma unroll
        for (int i = 0; i < 4; ++i)
            a[i] = *reinterpret_cast<const bf16x8*>(&As[(wrow + i * 16 + l15) * 32 + quad * 8]);
        #pragma unroll
        for (int j = 0; j < 4; ++j)
            b[j] = *reinterpret_cast<const bf16x8*>(&Bs[(wcol + j * 16 + l15) * 32 + quad * 8]);
        #pragma unroll
        for (int i = 0; i < 4; ++i)
            #pragma unroll
            for (int j = 0; j < 4; ++j)
                acc[i][j] = __builtin_amdgcn_mfma_f32_16x16x32_bf16(a[i], b[j], acc[i][j], 0, 0, 0);
    }

    // Q pre-scale: 0.125 (1/sqrt(DK)) * log2(e), folded so attn uses raw exp2.
    const float emul = (mode == 0 && z == 0 && mode_override < 0) ? 0.18033688011112042f : 1.0f;

    #pragma unroll
    for (int i = 0; i < 4; ++i) {
        #pragma unroll
        for (int j = 0; j < 4; ++j) {
            const int gc  = col0 + wcol + j * 16 + l15;
            const float bv = bias[gc];
            const int gr0 = row0 + wrow + i * 16 + quad * 4;
            if (mode == 3) {
                float* df = (float*)dst;
                #pragma unroll
                for (int r = 0; r < 4; ++r)
                    df[(size_t)(gr0 + r) * 1024 + gc] = acc[i][j][r] + bv;
            } else if (mode == 2) {
                u16* dp = (u16*)dst;
                const int b = gr0 >> 11, s = gr0 & 2047;
                const int h = gc >> 6,  dk = gc & 63;
                u16x4 pk;
                pk[0] = f2bf(acc[i][j][0] + bv);
                pk[1] = f2bf(acc[i][j][1] + bv);
                pk[2] = f2bf(acc[i][j][2] + bv);
                pk[3] = f2bf(acc[i][j][3] + bv);
                *reinterpret_cast<u16x4*>(dp + ((size_t)((b * 16 + h) * 64 + dk)) * 2048 + s) = pk;
            } else {
                u16* dp = (u16*)dst;
                #pragma unroll
                for (int r = 0; r < 4; ++r) {
                    const int gr = gr0 + r;
                    const int b = gr >> 11, s = gr & 2047;
                    const int h = gc >> 6, dk = gc & 63;
                    dp[((size_t)((b * 16 + h) * 2048 + s)) * 64 + dk] = f2bf((acc[i][j][r] + bv) * emul);
                }
            }
        }
    }
}

// ---------------------------------------------------------------------------
// MFMA flash attention v2: 32x32x16 MFMA, swapped QK^T (Z = K·Q^T) so the
// softmax row lives in registers (q = lane&31 matches PV A-operand rows).
// P -> bf16 A-fragments via v_cvt_pk_bf16_f32 + 4x ds_bpermute (lane^32) —
// no P LDS round-trip, no extra barrier. Direct-exp (exp2, Q pre-scaled by
// 0.125*log2e in the projection GEMM; overflow-safe, validated in round 6).
// LDS: K/V tiles as 16B chunks chunk(cb,r) -> cb*512 + (r^cb)*8 u16:
// fragment reads are contiguous 512B per half-wave and staging writes hit
// distinct banks per 8-lane phase -> ~zero bank conflicts.
// Block = 4 waves, 128 q rows (32/wave); 512 blocks, XCD-contiguous swizzle
// (each XCD's L2 keeps 4 heads' K/V = 2MB < 4MB).
// ---------------------------------------------------------------------------
__global__ __launch_bounds__(256) void attn_fused(
    const u16* __restrict__ Qb, const u16* __restrict__ Kb,
    const u16* __restrict__ Vt, const int* __restrict__ mask,
    u16* __restrict__ ctx)
{
    __shared__ __align__(16) u16 Ks[8 * 512];
    __shared__ __align__(16) u16 Vs[8 * 512];
    __shared__ float Ls[4 * 32];

    const int tid  = threadIdx.x;
    const int w    = tid >> 6;
    const int lane = tid & 63;
    const int l31  = lane & 31;
    const int hi   = lane >> 5;

    // bijective XCD-contiguous swizzle: 512 blocks = 8 XCDs x 64
    const int id = blockIdx.x;
    const int sw = (id & 7) * 64 + (id >> 3);
    const int bh = sw >> 4;
    const int q0 = (sw & 15) * 128;
    const int b  = bh >> 4, h = bh & 15;

    const u16* Qp = Qb + (size_t)bh * 2048 * 64;
    const u16* Kp = Kb + (size_t)bh * 2048 * 64;
    const u16* Vp = Vt + (size_t)bh * 64 * 2048;
    const int* mp = mask + b * 2048;

    // Q fragments (B-operand: lane holds Q[q=l31][d = s*16 + hi*8 + j])
    bf16x8 qf[4];
    {
        const u16* qrow = Qp + (size_t)(q0 + w * 32 + l31) * 64 + hi * 8;
        #pragma unroll
        for (int s = 0; s < 4; ++s)
            qf[s] = *reinterpret_cast<const bf16x8*>(qrow + s * 16);
    }

    // staging: thread covers chunks (cb = tid&7, r = tid>>3) and (cb, r+32)
    const int scb = tid & 7, sr = tid >> 3;
    const u16* kg0 = Kp + (size_t)sr * 64 + scb * 8;
    const u16* vg0 = Vp + (size_t)sr * 2048 + scb * 8;
    u16* kd0 = &Ks[scb * 512 + ((sr     ) ^ scb) * 8];
    u16* kd1 = &Ks[scb * 512 + ((sr + 32) ^ scb) * 8];
    u16* vd0 = &Vs[scb * 512 + ((sr     ) ^ scb) * 8];
    u16* vd1 = &Vs[scb * 512 + ((sr + 32) ^ scb) * 8];

    u16x8 kr0 = *reinterpret_cast<const u16x8*>(kg0);
    u16x8 kr1 = *reinterpret_cast<const u16x8*>(kg0 + 32 * 64);
    u16x8 vr0 = *reinterpret_cast<const u16x8*>(vg0);
    u16x8 vr1 = *reinterpret_cast<const u16x8*>(vg0 + 32 * 2048);
    int mreg = mp[lane];

    f32x16 accO0 = {}, accO1 = {};
    float la0 = 0.f, la1 = 0.f, la2 = 0.f, la3 = 0.f;
    const int paddr = (lane ^ 32) << 2;

    for (int t = 0; t < 32; ++t) {
        const int kk = t * 64;
        __syncthreads();                       // previous tile's reads done
        *reinterpret_cast<u16x8*>(kd0) = kr0;
        *reinterpret_cast<u16x8*>(kd1) = kr1;
        *reinterpret_cast<u16x8*>(vd0) = vr0;
        *reinterpret_cast<u16x8*>(vd1) = vr1;
        int mnext = 1;
        if (t < 31) {                          // prefetch next tile into regs
            const u16* kg = kg0 + (size_t)(kk + 64) * 64;
            const u16* vg = vg0 + (kk + 64);
            kr0 = *reinterpret_cast<const u16x8*>(kg);
            kr1 = *reinterpret_cast<const u16x8*>(kg + 32 * 64);
            vr0 = *reinterpret_cast<const u16x8*>(vg);
            vr1 = *reinterpret_cast<const u16x8*>(vg + 32 * 2048);
            mnext = mp[kk + 64 + lane];
        }
        __syncthreads();                       // tile t visible

        const bool fullmask = (__ballot(mreg != 0) == ~0ull);
        mreg = mnext;

        #pragma unroll
        for (int hf = 0; hf < 2; ++hf) {
            // Z = K·Q^T : Z[k = (r&3)+8*(r>>2)+4*hi][q = l31]
            f32x16 z = {};
            #pragma unroll
            for (int s = 0; s < 4; ++s) {
                const int cb = s * 2 + hi;
                const bf16x8 ak = *reinterpret_cast<const bf16x8*>(
                    &Ks[cb * 512 + ((hf * 32 + l31) ^ cb) * 8]);
                z = __builtin_amdgcn_mfma_f32_32x32x16_bf16(ak, qf[s], z, 0, 0, 0);
            }
            float p[16];
            #pragma unroll
            for (int r = 0; r < 16; ++r) p[r] = exp2_hw(z[r]);
            if (!fullmask) {                   // rare general-mask path
                #pragma unroll
                for (int r = 0; r < 16; ++r) {
                    const int kv = kk + hf * 32 + (r & 3) + 8 * (r >> 2) + 4 * hi;
                    if (mp[kv] == 0) p[r] = 0.f;
                }
            }
            la0 += p[0] + p[4] + p[8]  + p[12];
            la1 += p[1] + p[5] + p[9]  + p[13];
            la2 += p[2] + p[6] + p[10] + p[14];
            la3 += p[3] + p[7] + p[11] + p[15];

            // pack P -> bf16 pairs (ascending k per hi-half)
            const uint32_t wd0 = cvt_pk_bf16(p[0],  p[1]);
            const uint32_t wd1 = cvt_pk_bf16(p[2],  p[3]);
            const uint32_t wd2 = cvt_pk_bf16(p[4],  p[5]);
            const uint32_t wd3 = cvt_pk_bf16(p[6],  p[7]);
            const uint32_t wd4 = cvt_pk_bf16(p[8],  p[9]);
            const uint32_t wd5 = cvt_pk_bf16(p[10], p[11]);
            const uint32_t wd6 = cvt_pk_bf16(p[12], p[13]);
            const uint32_t wd7 = cvt_pk_bf16(p[14], p[15]);
            // exchange with lane^32 to assemble A-fragments (k = hi*8+j)
            const uint32_t s0 = hi ? wd0 : wd2;
            const uint32_t s1 = hi ? wd1 : wd3;
            const uint32_t s2 = hi ? wd4 : wd6;
            const uint32_t s3 = hi ? wd5 : wd7;
            const uint32_t r0 = (uint32_t)__builtin_amdgcn_ds_bpermute(paddr, (int)s0);
            const uint32_t r1 = (uint32_t)__builtin_amdgcn_ds_bpermute(paddr, (int)s1);
            const uint32_t r2 = (uint32_t)__builtin_amdgcn_ds_bpermute(paddr, (int)s2);
            const uint32_t r3 = (uint32_t)__builtin_amdgcn_ds_bpermute(paddr, (int)s3);
            union { uint32_t u[4]; bf16x8 v; } A0, A1;
            A0.u[0] = hi ? r0  : wd0;
            A0.u[1] = hi ? r1  : wd1;
            A0.u[2] = hi ? wd2 : r0;
            A0.u[3] = hi ? wd3 : r1;
            A1.u[0] = hi ? r2  : wd4;
            A1.u[1] = hi ? r3  : wd5;
            A1.u[2] = hi ? wd6 : r2;
            A1.u[3] = hi ? wd7 : r3;

            // O += P V : B-frag from V^T rows d = nt*32 + l31, k chunks
            const int ck0 = hf * 4 + hi;
            const int ck1 = hf * 4 + 2 + hi;
            const bf16x8 bv00 = *reinterpret_cast<const bf16x8*>(&Vs[ck0 * 512 + ((     l31) ^ ck0) * 8]);
            const bf16x8 bv01 = *reinterpret_cast<const bf16x8*>(&Vs[ck1 * 512 + ((     l31) ^ ck1) * 8]);
            const bf16x8 bv10 = *reinterpret_cast<const bf16x8*>(&Vs[ck0 * 512 + ((32 + l31) ^ ck0) * 8]);
            const bf16x8 bv11 = *reinterpret_cast<const bf16x8*>(&Vs[ck1 * 512 + ((32 + l31) ^ ck1) * 8]);
            accO0 = __builtin_amdgcn_mfma_f32_32x32x16_bf16(A0.v, bv00, accO0, 0, 0, 0);
            accO0 = __builtin_amdgcn_mfma_f32_32x32x16_bf16(A1.v, bv01, accO0, 0, 0, 0);
            accO1 = __builtin_amdgcn_mfma_f32_32x32x16_bf16(A0.v, bv10, accO1, 0, 0, 0);
            accO1 = __builtin_amdgcn_mfma_f32_32x32x16_bf16(A1.v, bv11, accO1, 0, 0, 0);
        }
    }

    // l reduction: lane holds partial sum for q = l31 over its k subset;
    // partner (lane^32) has the rest.
    float l_acc = (la0 + la1) + (la2 + la3);
    l_acc += __shfl_xor(l_acc, 32);
    const float inv = 1.0f / l_acc;
    if (lane < 32) Ls[w * 32 + l31] = inv;
    __syncthreads();

    #pragma unroll
    for (int r = 0; r < 16; ++r) {
        const int qr = (r & 3) + 8 * (r >> 2) + 4 * hi;
        const float iv = Ls[w * 32 + qr];
        u16* row = ctx + (size_t)(b * 2048 + q0 + w * 32 + qr) * 1024 + h * 64;
        row[l31]      = f2bf(accO0[r] * iv);
        row[32 + l31] = f2bf(accO1[r] * iv);
    }
}

// ---------------------------------------------------------------------------
extern "C" void kernel_launch(void* const* d_in, const int* in_sizes, int n_in,
                              void* d_out, int out_size, void* d_ws, size_t ws_size,
                              hipStream_t stream) {
    const float* query = (const float*)d_in[0];
    const float* key   = (const float*)d_in[1];
    const float* value = (const float*)d_in[2];
    const int*   mask  = (const int*)d_in[3];
    const float* Wq = (const float*)d_in[4];
    const float* bq = (const float*)d_in[5];
    const float* Wk = (const float*)d_in[6];
    const float* bk = (const float*)d_in[7];
    const float* Wv = (const float*)d_in[8];
    const float* bv = (const float*)d_in[9];
    const float* Wo = (const float*)d_in[10];
    const float* bo = (const float*)d_in[11];
    float* out = (float*)d_out;

    u16* ws   = (u16*)d_ws;                  // offsets in u16 elems
    u16* Xq   = ws;                          // 4194304 each (8MB)
    u16* Xk   = ws + 4194304;
    u16* Xv   = ws + 8388608;
    u16* WqT  = ws + 12582912;               // 1048576 each (2MB)
    u16* WkT  = ws + 13631488;
    u16* WvT  = ws + 14680064;
    u16* WoT  = ws + 15728640;
    u16* Qb   = ws + 16777216;               // 8MB each
    u16* Kb   = ws + 20971520;
    u16* Vt   = ws + 25165824;               // high-water: 56MB
    u16* ctx  = Xq;                          // alias: Xq dead after proj GEMMs

    dim3 blk(256);
    cvt_all<<<dim3(1024, 1, 7), blk, 0, stream>>>(query, key, value, Wq, Wk, Wv, Wo,
                                                  Xq, Xk, Xv, WqT, WkT, WvT, WoT);
    gemm_bt<<<dim3(32, 8, 3),  blk, 0, stream>>>(Xq, Xk, Xv, WqT, WkT, WvT,
                                                 bq, bk, bv, Qb, Kb, Vt, -1);
    attn_fused<<<dim3(512), blk, 0, stream>>>(Qb, Kb, Vt, mask, ctx);
    gemm_bt<<<dim3(32, 8, 1),  blk, 0, stream>>>(ctx, ctx, ctx, WoT, WoT, WoT,
                                                 bo, bo, bo, out, out, out, 3);
}

// Round 2
// 236.135 us; speedup vs baseline: 1.1261x; 1.0414x over previous
//
#include <hip/hip_runtime.h>
#include <stdint.h>

// MHA: B=2, S=2048, D=1024, H=16, DK=64.
// Inputs fp32, mask int32, output fp32 (bf16-grade tolerance).
// Internal: bf16 (pre-converted X, pre-transposed W).
typedef unsigned short u16;
typedef __bf16 bf16x8 __attribute__((ext_vector_type(8), may_alias));
typedef unsigned short u16x8 __attribute__((ext_vector_type(8), may_alias));
typedef unsigned short u16x4 __attribute__((ext_vector_type(4), may_alias));
typedef float f32x4 __attribute__((ext_vector_type(4)));
typedef float f32x16 __attribute__((ext_vector_type(16)));

__device__ __forceinline__ u16 f2bf(float f) {
    union { float f; uint32_t i; } v; v.f = f;
    return (u16)((v.i + 0x7FFFu + ((v.i >> 16) & 1u)) >> 16);
}

__device__ __forceinline__ float exp2_hw(float x) {
#if __has_builtin(__builtin_amdgcn_exp2f)
    return __builtin_amdgcn_exp2f(x);
#else
    float r; asm("v_exp_f32 %0, %1" : "=v"(r) : "v"(x)); return r;
#endif
}

__device__ __forceinline__ uint32_t cvt_pk_bf16(float a, float b) {
    uint32_t r;
    asm("v_cvt_pk_bf16_f32 %0, %1, %2" : "=v"(r) : "v"(a), "v"(b));
    return r;
}

// async 16B global -> LDS (wave-uniform LDS base + lane*16; m97 pattern)
__device__ __forceinline__ void gld_lds16(const u16* g, u16* l) {
    __builtin_amdgcn_global_load_lds(
        (const __attribute__((address_space(1))) unsigned int*)g,
        (__attribute__((address_space(3))) unsigned int*)l, 16, 0, 0);
}

// ---------------------------------------------------------------------------
// cvt_all: z<3 -> X fp32->bf16 copy (1024 blocks, 16 elem/thr);
//          z>=3 -> W fp32 [k][n] -> bf16 [n][k] transpose (256 blocks active).
// grid (1024, 1, 7).
// ---------------------------------------------------------------------------
__global__ __launch_bounds__(256) void cvt_all(
    const float* __restrict__ s0, const float* __restrict__ s1, const float* __restrict__ s2,
    const float* __restrict__ w0, const float* __restrict__ w1,
    const float* __restrict__ w2, const float* __restrict__ w3,
    u16* __restrict__ d0, u16* __restrict__ d1, u16* __restrict__ d2,
    u16* __restrict__ t0, u16* __restrict__ t1,
    u16* __restrict__ t2, u16* __restrict__ t3)
{
    __shared__ float L[64][65];
    const int z = blockIdx.z;
    const int tid = threadIdx.x;
    if (z < 3) {
        const float* s = (z == 0) ? s0 : (z == 1) ? s1 : s2;
        u16*         d = (z == 0) ? d0 : (z == 1) ? d1 : d2;
        const size_t base = ((size_t)blockIdx.x * 256 + tid) * 16;
        #pragma unroll
        for (int p = 0; p < 2; ++p) {
            float4 a = *reinterpret_cast<const float4*>(s + base + p * 8);
            float4 b = *reinterpret_cast<const float4*>(s + base + p * 8 + 4);
            u16x8 o;
            o[0] = f2bf(a.x); o[1] = f2bf(a.y); o[2] = f2bf(a.z); o[3] = f2bf(a.w);
            o[4] = f2bf(b.x); o[5] = f2bf(b.y); o[6] = f2bf(b.z); o[7] = f2bf(b.w);
            *reinterpret_cast<u16x8*>(d + base + p * 8) = o;
        }
    } else {
        if (blockIdx.x >= 256) return;
        const int zi = z - 3;
        const float* w = (zi == 0) ? w0 : (zi == 1) ? w1 : (zi == 2) ? w2 : w3;
        u16*         t = (zi == 0) ? t0 : (zi == 1) ? t1 : (zi == 2) ? t2 : t3;
        const int k0 = (blockIdx.x & 15) * 64, n0 = (blockIdx.x >> 4) * 64;
        const int rr = tid >> 6, cc = tid & 63;
        #pragma unroll
        for (int p = 0; p < 16; ++p)
            L[p * 4 + rr][cc] = w[(size_t)(k0 + p * 4 + rr) * 1024 + n0 + cc];
        __syncthreads();
        #pragma unroll
        for (int p = 0; p < 16; ++p)
            t[(size_t)(n0 + p * 4 + rr) * 1024 + k0 + cc] = f2bf(L[cc][p * 4 + rr]);
    }
}

// ---------------------------------------------------------------------------
// m97-style GEMM: 128x128 tile, BK=32, global_load_lds width=16.
// grid (32, 8, Z).  mode-0 z==0 (Q projection) output is pre-scaled by
// 0.125*log2(e) so attention can use raw v_exp (exp2) with no per-element mul.
// ---------------------------------------------------------------------------
__global__ __launch_bounds__(256) void gemm_bt(
    const u16* __restrict__ A0, const u16* __restrict__ A1, const u16* __restrict__ A2,
    const u16* __restrict__ B0, const u16* __restrict__ B1, const u16* __restrict__ B2,
    const float* __restrict__ c0, const float* __restrict__ c1, const float* __restrict__ c2,
    void* __restrict__ d0, void* __restrict__ d1, void* __restrict__ d2,
    int mode_override)
{
    __shared__ u16 As[128 * 32];
    __shared__ u16 Bs[128 * 32];

    const int z = blockIdx.z;
    const u16* A = (z == 0) ? A0 : (z == 1) ? A1 : A2;
    const u16* BT = (z == 0) ? B0 : (z == 1) ? B1 : B2;
    const float* bias = (z == 0) ? c0 : (z == 1) ? c1 : c2;
    void* dst = (z == 0) ? d0 : (z == 1) ? d1 : d2;
    const int mode = (mode_override >= 0) ? mode_override : ((z == 2) ? 2 : 0);

    const int tid  = threadIdx.x;
    const int wave = tid >> 6, lane = tid & 63;
    const int quad = lane >> 4, l15 = lane & 15;
    const int row0 = blockIdx.x * 128, col0 = blockIdx.y * 128;
    const int wrow = (wave >> 1) * 64, wcol = (wave & 1) * 64;

    f32x4 acc[4][4] = {};

    for (int k0 = 0; k0 < 1024; k0 += 32) {
        __syncthreads();
        #pragma unroll
        for (int j = 0; j < 2; ++j) {
            const int idx = j * 256 + tid;
            const int r = idx >> 2, kc = (idx & 3) * 8;
            gld_lds16(A  + (size_t)(row0 + r) * 1024 + k0 + kc,
                      &As[(size_t)(j * 256 + wave * 64) * 8]);
            gld_lds16(BT + (size_t)(col0 + r) * 1024 + k0 + kc,
                      &Bs[(size_t)(j * 256 + wave * 64) * 8]);
        }
        __syncthreads();

        bf16x8 a[4], b[4];
        #pragma unroll
        for (int i = 0; i < 4; ++i)
            a[i] = *reinterpret_cast<const bf16x8*>(&As[(wrow + i * 16 + l15) * 32 + quad * 8]);
        #pragma unroll
        for (int j = 0; j < 4; ++j)
            b[j] = *reinterpret_cast<const bf16x8*>(&Bs[(wcol + j * 16 + l15) * 32 + quad * 8]);
        #pragma unroll
        for (int i = 0; i < 4; ++i)
            #pragma unroll
            for (int j = 0; j < 4; ++j)
                acc[i][j] = __builtin_amdgcn_mfma_f32_16x16x32_bf16(a[i], b[j], acc[i][j], 0, 0, 0);
    }

    // Q pre-scale: 0.125 (1/sqrt(DK)) * log2(e), folded so attn uses raw exp2.
    const float emul = (mode == 0 && z == 0 && mode_override < 0) ? 0.18033688011112042f : 1.0f;

    #pragma unroll
    for (int i = 0; i < 4; ++i) {
        #pragma unroll
        for (int j = 0; j < 4; ++j) {
            const int gc  = col0 + wcol + j * 16 + l15;
            const float bv = bias[gc];
            const int gr0 = row0 + wrow + i * 16 + quad * 4;
            if (mode == 3) {
                float* df = (float*)dst;
                #pragma unroll
                for (int r = 0; r < 4; ++r)
                    df[(size_t)(gr0 + r) * 1024 + gc] = acc[i][j][r] + bv;
            } else if (mode == 2) {
                u16* dp = (u16*)dst;
                const int b = gr0 >> 11, s = gr0 & 2047;
                const int h = gc >> 6,  dk = gc & 63;
                u16x4 pk;
                pk[0] = f2bf(acc[i][j][0] + bv);
                pk[1] = f2bf(acc[i][j][1] + bv);
                pk[2] = f2bf(acc[i][j][2] + bv);
                pk[3] = f2bf(acc[i][j][3] + bv);
                *reinterpret_cast<u16x4*>(dp + ((size_t)((b * 16 + h) * 64 + dk)) * 2048 + s) = pk;
            } else {
                u16* dp = (u16*)dst;
                #pragma unroll
                for (int r = 0; r < 4; ++r) {
                    const int gr = gr0 + r;
                    const int b = gr >> 11, s = gr & 2047;
                    const int h = gc >> 6, dk = gc & 63;
                    dp[((size_t)((b * 16 + h) * 2048 + s)) * 64 + dk] = f2bf((acc[i][j][r] + bv) * emul);
                }
            }
        }
    }
}

// ---------------------------------------------------------------------------
// MFMA flash attention v3: 8 waves/block (512 thr), in-block K-split.
// Wave w = (qw = w&3, kh = w>>2): q rows q0+qw*32..+32, key half kh of each
// staged 64-key tile. 4096 total waves -> 4 waves/SIMD (vs 2 in v2) to hide
// the serial QK->exp->bpermute->PV chain. Double-buffered LDS: ONE barrier
// per iteration; global loads issued at iter top, ds_write after compute
// (T14 async-stage). Partial accO/l combined once at the end via LDS
// (aliased onto the dead staging buffers).
// Softmax in-register via swapped QK^T (Z = K·Q^T), cvt_pk_bf16 + lane^32
// ds_bpermute to build PV A-fragments; direct exp2 (Q pre-scaled by
// 0.125*log2e in the projection GEMM).
// LDS chunk layout chunk(cb,r) -> cb*512 + (r^cb)*8 u16: conflict-free
// staging writes and fragment reads (verified 0 conflicts in v2).
// ---------------------------------------------------------------------------
__global__ __launch_bounds__(512, 4) void attn_fused(
    const u16* __restrict__ Qb, const u16* __restrict__ Kb,
    const u16* __restrict__ Vt, const int* __restrict__ mask,
    u16* __restrict__ ctx)
{
    // 33 KB: double buffer 2 x (Ks 4096 + Vs 4096) u16 = 32 KB;
    // end-combine aliases the whole region as float[8448] = 33792 B.
    __shared__ __align__(16) u16 SMEM[16896];

    const int tid  = threadIdx.x;
    const int w    = tid >> 6;
    const int lane = tid & 63;
    const int l31  = lane & 31;
    const int hi   = lane >> 5;
    const int qw   = w & 3;
    const int kh   = w >> 2;

    // bijective XCD-contiguous swizzle: 512 blocks = 8 XCDs x 64
    const int id = blockIdx.x;
    const int sw = (id & 7) * 64 + (id >> 3);
    const int bh = sw >> 4;
    const int q0 = (sw & 15) * 128;
    const int b  = bh >> 4, h = bh & 15;

    const u16* Qp = Qb + (size_t)bh * 2048 * 64;
    const u16* Kp = Kb + (size_t)bh * 2048 * 64;
    const u16* Vp = Vt + (size_t)bh * 64 * 2048;
    const int* mp = mask + b * 2048;

    // Q fragments (B-operand): lane holds Q[q = q0+qw*32+l31][d = s*16+hi*8+j]
    bf16x8 qf[4];
    {
        const u16* qrow = Qp + (size_t)(q0 + qw * 32 + l31) * 64 + hi * 8;
        #pragma unroll
        for (int s = 0; s < 4; ++s)
            qf[s] = *reinterpret_cast<const bf16x8*>(qrow + s * 16);
    }

    // staging: 512 threads cover 512 16B chunks of K and of V^T per tile
    const int scb = tid & 7, sr = tid >> 3;          // sr in [0,64)
    const u16* kg0 = Kp + (size_t)sr * 64 + scb * 8;
    const u16* vg0 = Vp + (size_t)sr * 2048 + scb * 8;
    const int dK = scb * 512 + (sr ^ scb) * 8;       // chunk offset within a region

    // prologue: tile 0 -> buffer 0
    {
        u16x8 kr = *reinterpret_cast<const u16x8*>(kg0);
        u16x8 vr = *reinterpret_cast<const u16x8*>(vg0);
        *reinterpret_cast<u16x8*>(&SMEM[dK])        = kr;
        *reinterpret_cast<u16x8*>(&SMEM[4096 + dK]) = vr;
    }
    int mreg = mp[lane];
    __syncthreads();

    f32x16 accO0 = {}, accO1 = {};
    float la0 = 0.f, la1 = 0.f, la2 = 0.f, la3 = 0.f;
    const int paddr = (lane ^ 32) << 2;

    int cur = 0;
    for (int t = 0; t < 32; ++t) {
        const int kk = t * 64;
        // issue next-tile loads early (consumed by ds_write after compute)
        u16x8 krn, vrn; int mnext = 1;
        if (t < 31) {
            krn = *reinterpret_cast<const u16x8*>(kg0 + (size_t)(kk + 64) * 64);
            vrn = *reinterpret_cast<const u16x8*>(vg0 + (kk + 64));
            mnext = mp[kk + 64 + lane];
        }
        const u16* Kb_ = &SMEM[cur * 8192];
        const u16* Vb_ = &SMEM[cur * 8192 + 4096];

        const bool fullmask = (__ballot(mreg != 0) == ~0ull);

        // Z = K·Q^T over this wave's key half: Z[key rr][q = l31]
        f32x16 z = {};
        #pragma unroll
        for (int s = 0; s < 4; ++s) {
            const int cb = s * 2 + hi;
            const bf16x8 ak = *reinterpret_cast<const bf16x8*>(
                &Kb_[cb * 512 + (((kh * 32 + l31)) ^ cb) * 8]);
            z = __builtin_amdgcn_mfma_f32_32x32x16_bf16(ak, qf[s], z, 0, 0, 0);
        }
        float p[16];
        #pragma unroll
        for (int r = 0; r < 16; ++r) p[r] = exp2_hw(z[r]);
        if (!fullmask) {                   // rare general-mask path
            #pragma unroll
            for (int r = 0; r < 16; ++r) {
                const int kv = kk + kh * 32 + (r & 3) + 8 * (r >> 2) + 4 * hi;
                if (mp[kv] == 0) p[r] = 0.f;
            }
        }
        la0 += p[0] + p[4] + p[8]  + p[12];
        la1 += p[1] + p[5] + p[9]  + p[13];
        la2 += p[2] + p[6] + p[10] + p[14];
        la3 += p[3] + p[7] + p[11] + p[15];

        // pack P -> bf16 pairs (ascending key per hi-half)
        const uint32_t wd0 = cvt_pk_bf16(p[0],  p[1]);
        const uint32_t wd1 = cvt_pk_bf16(p[2],  p[3]);
        const uint32_t wd2 = cvt_pk_bf16(p[4],  p[5]);
        const uint32_t wd3 = cvt_pk_bf16(p[6],  p[7]);
        const uint32_t wd4 = cvt_pk_bf16(p[8],  p[9]);
        const uint32_t wd5 = cvt_pk_bf16(p[10], p[11]);
        const uint32_t wd6 = cvt_pk_bf16(p[12], p[13]);
        const uint32_t wd7 = cvt_pk_bf16(p[14], p[15]);
        // exchange with lane^32 to assemble A-fragments (k = hi*8+j)
        const uint32_t s0 = hi ? wd0 : wd2;
        const uint32_t s1 = hi ? wd1 : wd3;
        const uint32_t s2 = hi ? wd4 : wd6;
        const uint32_t s3 = hi ? wd5 : wd7;
        const uint32_t r0 = (uint32_t)__builtin_amdgcn_ds_bpermute(paddr, (int)s0);
        const uint32_t r1 = (uint32_t)__builtin_amdgcn_ds_bpermute(paddr, (int)s1);
        const uint32_t r2 = (uint32_t)__builtin_amdgcn_ds_bpermute(paddr, (int)s2);
        const uint32_t r3 = (uint32_t)__builtin_amdgcn_ds_bpermute(paddr, (int)s3);
        union { uint32_t u[4]; bf16x8 v; } A0, A1;
        A0.u[0] = hi ? r0  : wd0;
        A0.u[1] = hi ? r1  : wd1;
        A0.u[2] = hi ? wd2 : r0;
        A0.u[3] = hi ? wd3 : r1;
        A1.u[0] = hi ? r2  : wd4;
        A1.u[1] = hi ? r3  : wd5;
        A1.u[2] = hi ? wd6 : r2;
        A1.u[3] = hi ? wd7 : r3;

        // O += P V over this wave's key half
        const int ck0 = kh * 4 + hi;
        const int ck1 = kh * 4 + 2 + hi;
        const bf16x8 bv00 = *reinterpret_cast<const bf16x8*>(&Vb_[ck0 * 512 + ((     l31) ^ ck0) * 8]);
        const bf16x8 bv01 = *reinterpret_cast<const bf16x8*>(&Vb_[ck1 * 512 + ((     l31) ^ ck1) * 8]);
        const bf16x8 bv10 = *reinterpret_cast<const bf16x8*>(&Vb_[ck0 * 512 + ((32 + l31) ^ ck0) * 8]);
        const bf16x8 bv11 = *reinterpret_cast<const bf16x8*>(&Vb_[ck1 * 512 + ((32 + l31) ^ ck1) * 8]);
        accO0 = __builtin_amdgcn_mfma_f32_32x32x16_bf16(A0.v, bv00, accO0, 0, 0, 0);
        accO0 = __builtin_amdgcn_mfma_f32_32x32x16_bf16(A1.v, bv01, accO0, 0, 0, 0);
        accO1 = __builtin_amdgcn_mfma_f32_32x32x16_bf16(A0.v, bv10, accO1, 0, 0, 0);
        accO1 = __builtin_amdgcn_mfma_f32_32x32x16_bf16(A1.v, bv11, accO1, 0, 0, 0);

        // stage next tile into the other buffer (after this buffer's reads)
        if (t < 31) {
            const int nb = (cur ^ 1) * 8192;
            *reinterpret_cast<u16x8*>(&SMEM[nb + dK])        = krn;
            *reinterpret_cast<u16x8*>(&SMEM[nb + 4096 + dK]) = vrn;
        }
        __syncthreads();   // reads of buf[cur] done AND buf[cur^1] visible
        cur ^= 1;
        mreg = mnext;
    }

    // ---- combine kh halves (staging buffers dead; alias as float) ----
    // F: acc0 [0,4096), acc1 [4096,8192), l [8192,8320), inv [8320,8448)
    float l_part = (la0 + la1) + (la2 + la3);
    l_part += __shfl_xor(l_part, 32);      // this wave's full key-half sum, q=l31
    float* F = (float*)SMEM;
    if (kh) {
        #pragma unroll
        for (int r = 0; r < 16; ++r) F[qw * 1024 + r * 64 + lane] = accO0[r];
        #pragma unroll
        for (int r = 0; r < 16; ++r) F[4096 + qw * 1024 + r * 64 + lane] = accO1[r];
        if (lane < 32) F[8192 + qw * 32 + l31] = l_part;
    }
    __syncthreads();
    if (!kh && lane < 32)
        F[8320 + qw * 32 + l31] = 1.0f / (l_part + F[8192 + qw * 32 + l31]);
    __syncthreads();
    if (!kh) {
        #pragma unroll
        for (int r = 0; r < 16; ++r) {
            const int qr = (r & 3) + 8 * (r >> 2) + 4 * hi;
            const float iv = F[8320 + qw * 32 + qr];
            const float o0 = accO0[r] + F[qw * 1024 + r * 64 + lane];
            const float o1 = accO1[r] + F[4096 + qw * 1024 + r * 64 + lane];
            u16* row = ctx + (size_t)(b * 2048 + q0 + qw * 32 + qr) * 1024 + h * 64;
            row[l31]      = f2bf(o0 * iv);
            row[32 + l31] = f2bf(o1 * iv);
        }
    }
}

// ---------------------------------------------------------------------------
extern "C" void kernel_launch(void* const* d_in, const int* in_sizes, int n_in,
                              void* d_out, int out_size, void* d_ws, size_t ws_size,
                              hipStream_t stream) {
    const float* query = (const float*)d_in[0];
    const float* key   = (const float*)d_in[1];
    const float* value = (const float*)d_in[2];
    const int*   mask  = (const int*)d_in[3];
    const float* Wq = (const float*)d_in[4];
    const float* bq = (const float*)d_in[5];
    const float* Wk = (const float*)d_in[6];
    const float* bk = (const float*)d_in[7];
    const float* Wv = (const float*)d_in[8];
    const float* bv = (const float*)d_in[9];
    const float* Wo = (const float*)d_in[10];
    const float* bo = (const float*)d_in[11];
    float* out = (float*)d_out;

    u16* ws   = (u16*)d_ws;                  // offsets in u16 elems
    u16* Xq   = ws;                          // 4194304 each (8MB)
    u16* Xk   = ws + 4194304;
    u16* Xv   = ws + 8388608;
    u16* WqT  = ws + 12582912;               // 1048576 each (2MB)
    u16* WkT  = ws + 13631488;
    u16* WvT  = ws + 14680064;
    u16* WoT  = ws + 15728640;
    u16* Qb   = ws + 16777216;               // 8MB each
    u16* Kb   = ws + 20971520;
    u16* Vt   = ws + 25165824;               // high-water: 56MB
    u16* ctx  = Xq;                          // alias: Xq dead after proj GEMMs

    dim3 blk(256);
    cvt_all<<<dim3(1024, 1, 7), blk, 0, stream>>>(query, key, value, Wq, Wk, Wv, Wo,
                                                  Xq, Xk, Xv, WqT, WkT, WvT, WoT);
    gemm_bt<<<dim3(32, 8, 3),  blk, 0, stream>>>(Xq, Xk, Xv, WqT, WkT, WvT,
                                                 bq, bk, bv, Qb, Kb, Vt, -1);
    attn_fused<<<dim3(512), dim3(512), 0, stream>>>(Qb, Kb, Vt, mask, ctx);
    gemm_bt<<<dim3(32, 8, 1),  blk, 0, stream>>>(ctx, ctx, ctx, WoT, WoT, WoT,
                                                 bo, bo, bo, out, out, out, 3);
}

// Round 3
// 224.754 us; speedup vs baseline: 1.1832x; 1.0506x over previous
//
#include <hip/hip_runtime.h>
#include <stdint.h>

// MHA: B=2, S=2048, D=1024, H=16, DK=64.
// Inputs fp32, mask int32, output fp32 (bf16-grade tolerance).
// Internal: bf16 (pre-converted X, pre-transposed W).
typedef unsigned short u16;
typedef __bf16 bf16x8 __attribute__((ext_vector_type(8), may_alias));
typedef unsigned short u16x8 __attribute__((ext_vector_type(8), may_alias));
typedef unsigned short u16x4 __attribute__((ext_vector_type(4), may_alias));
typedef float f32x4 __attribute__((ext_vector_type(4)));
typedef float f32x16 __attribute__((ext_vector_type(16)));

__device__ __forceinline__ u16 f2bf(float f) {
    union { float f; uint32_t i; } v; v.f = f;
    return (u16)((v.i + 0x7FFFu + ((v.i >> 16) & 1u)) >> 16);
}

__device__ __forceinline__ float exp2_hw(float x) {
#if __has_builtin(__builtin_amdgcn_exp2f)
    return __builtin_amdgcn_exp2f(x);
#else
    float r; asm("v_exp_f32 %0, %1" : "=v"(r) : "v"(x)); return r;
#endif
}

__device__ __forceinline__ uint32_t cvt_pk_bf16(float a, float b) {
    uint32_t r;
    asm("v_cvt_pk_bf16_f32 %0, %1, %2" : "=v"(r) : "v"(a), "v"(b));
    return r;
}

// async 16B global -> LDS (wave-uniform LDS base + lane*16; m97 pattern)
__device__ __forceinline__ void gld_lds16(const u16* g, u16* l) {
    __builtin_amdgcn_global_load_lds(
        (const __attribute__((address_space(1))) unsigned int*)g,
        (__attribute__((address_space(3))) unsigned int*)l, 16, 0, 0);
}

// ---------------------------------------------------------------------------
// cvt_all: z<3 -> X fp32->bf16 copy (1024 blocks, 16 elem/thr);
//          z>=3 -> W fp32 [k][n] -> bf16 [n][k] transpose (256 blocks active).
// grid (1024, 1, 7).
// ---------------------------------------------------------------------------
__global__ __launch_bounds__(256) void cvt_all(
    const float* __restrict__ s0, const float* __restrict__ s1, const float* __restrict__ s2,
    const float* __restrict__ w0, const float* __restrict__ w1,
    const float* __restrict__ w2, const float* __restrict__ w3,
    u16* __restrict__ d0, u16* __restrict__ d1, u16* __restrict__ d2,
    u16* __restrict__ t0, u16* __restrict__ t1,
    u16* __restrict__ t2, u16* __restrict__ t3)
{
    __shared__ float L[64][65];
    const int z = blockIdx.z;
    const int tid = threadIdx.x;
    if (z < 3) {
        const float* s = (z == 0) ? s0 : (z == 1) ? s1 : s2;
        u16*         d = (z == 0) ? d0 : (z == 1) ? d1 : d2;
        const size_t base = ((size_t)blockIdx.x * 256 + tid) * 16;
        #pragma unroll
        for (int p = 0; p < 2; ++p) {
            float4 a = *reinterpret_cast<const float4*>(s + base + p * 8);
            float4 b = *reinterpret_cast<const float4*>(s + base + p * 8 + 4);
            u16x8 o;
            o[0] = f2bf(a.x); o[1] = f2bf(a.y); o[2] = f2bf(a.z); o[3] = f2bf(a.w);
            o[4] = f2bf(b.x); o[5] = f2bf(b.y); o[6] = f2bf(b.z); o[7] = f2bf(b.w);
            *reinterpret_cast<u16x8*>(d + base + p * 8) = o;
        }
    } else {
        if (blockIdx.x >= 256) return;
        const int zi = z - 3;
        const float* w = (zi == 0) ? w0 : (zi == 1) ? w1 : (zi == 2) ? w2 : w3;
        u16*         t = (zi == 0) ? t0 : (zi == 1) ? t1 : (zi == 2) ? t2 : t3;
        const int k0 = (blockIdx.x & 15) * 64, n0 = (blockIdx.x >> 4) * 64;
        const int rr = tid >> 6, cc = tid & 63;
        #pragma unroll
        for (int p = 0; p < 16; ++p)
            L[p * 4 + rr][cc] = w[(size_t)(k0 + p * 4 + rr) * 1024 + n0 + cc];
        __syncthreads();
        #pragma unroll
        for (int p = 0; p < 16; ++p)
            t[(size_t)(n0 + p * 4 + rr) * 1024 + k0 + cc] = f2bf(L[cc][p * 4 + rr]);
    }
}

// ---------------------------------------------------------------------------
// GEMM v2: 128x128 tile, BK=32, global_load_lds width=16, DOUBLE-BUFFERED
// LDS with prefetch-ahead staging (T3 minimum-2-phase): stage tile t+1 is
// issued BEFORE computing tile t; single __syncthreads per K-iter (its
// vmcnt(0)+lgkmcnt(0) drain lands after the MFMAs covered load latency).
// Chunk-XOR swizzle (c ^= (r>>1)&3, 16B granules) applied on the per-lane
// global SOURCE address (LDS dest stays linear for gld_lds) and on the
// fragment-read address: 8-way ds_read_b128 bank conflict -> 2-way (free).
// grid (32, 8, Z). mode-0 z==0 (Q proj) output pre-scaled by 0.125*log2(e).
// ---------------------------------------------------------------------------
__global__ __launch_bounds__(256) void gemm_bt(
    const u16* __restrict__ A0, const u16* __restrict__ A1, const u16* __restrict__ A2,
    const u16* __restrict__ B0, const u16* __restrict__ B1, const u16* __restrict__ B2,
    const float* __restrict__ c0, const float* __restrict__ c1, const float* __restrict__ c2,
    void* __restrict__ d0, void* __restrict__ d1, void* __restrict__ d2,
    int mode_override)
{
    __shared__ u16 As[2 * 4096];
    __shared__ u16 Bs[2 * 4096];

    const int z = blockIdx.z;
    const u16* A = (z == 0) ? A0 : (z == 1) ? A1 : A2;
    const u16* BT = (z == 0) ? B0 : (z == 1) ? B1 : B2;
    const float* bias = (z == 0) ? c0 : (z == 1) ? c1 : c2;
    void* dst = (z == 0) ? d0 : (z == 1) ? d1 : d2;
    const int mode = (mode_override >= 0) ? mode_override : ((z == 2) ? 2 : 0);

    const int tid  = threadIdx.x;
    const int wave = tid >> 6, lane = tid & 63;
    const int quad = lane >> 4, l15 = lane & 15;
    const int row0 = blockIdx.x * 128, col0 = blockIdx.y * 128;
    const int wrow = (wave >> 1) * 64, wcol = (wave & 1) * 64;

    // staging geometry (per j-step): idx = j*256+tid -> LDS slot (r = idx>>2,
    // c = idx&3); source chunk is XOR-swizzled so LDS[r][c] = global(r, c^sw(r))
    const int sidx0 = tid, sidx1 = 256 + tid;
    const int sr0 = sidx0 >> 2, sc0 = ((sidx0 & 3) ^ ((sr0 >> 1) & 3)) * 8;
    const int sr1 = sidx1 >> 2, sc1 = ((sidx1 & 3) ^ ((sr1 >> 1) & 3)) * 8;
    const size_t aoff0 = (size_t)(row0 + sr0) * 1024 + sc0;
    const size_t aoff1 = (size_t)(row0 + sr1) * 1024 + sc1;
    const size_t boff0 = (size_t)(col0 + sr0) * 1024 + sc0;
    const size_t boff1 = (size_t)(col0 + sr1) * 1024 + sc1;
    u16* const asl0 = &As[(size_t)(wave * 64) * 8];
    u16* const asl1 = &As[(size_t)(256 + wave * 64) * 8];
    u16* const bsl0 = &Bs[(size_t)(wave * 64) * 8];
    u16* const bsl1 = &Bs[(size_t)(256 + wave * 64) * 8];

    f32x4 acc[4][4] = {};

    // prologue: stage k0=0 into buffer 0
    gld_lds16(A + aoff0, asl0);
    gld_lds16(BT + boff0, bsl0);
    gld_lds16(A + aoff1, asl1);
    gld_lds16(BT + boff1, bsl1);
    __syncthreads();

    int cur = 0;
    for (int k0 = 0; k0 < 1024; k0 += 32) {
        // issue next tile's staging into the other buffer (async, no wait)
        if (k0 < 992) {
            const int nb = (cur ^ 1) * 4096;
            gld_lds16(A + aoff0 + (k0 + 32), asl0 + nb);
            gld_lds16(BT + boff0 + (k0 + 32), bsl0 + nb);
            gld_lds16(A + aoff1 + (k0 + 32), asl1 + nb);
            gld_lds16(BT + boff1 + (k0 + 32), bsl1 + nb);
        }

        const u16* Ab = &As[cur * 4096];
        const u16* Bb = &Bs[cur * 4096];
        bf16x8 a[4], b[4];
        #pragma unroll
        for (int i = 0; i < 4; ++i) {
            const int ar = wrow + i * 16 + l15;
            a[i] = *reinterpret_cast<const bf16x8*>(&Ab[ar * 32 + (quad ^ ((ar >> 1) & 3)) * 8]);
        }
        #pragma unroll
        for (int j = 0; j < 4; ++j) {
            const int br = wcol + j * 16 + l15;
            b[j] = *reinterpret_cast<const bf16x8*>(&Bb[br * 32 + (quad ^ ((br >> 1) & 3)) * 8]);
        }
        #pragma unroll
        for (int i = 0; i < 4; ++i)
            #pragma unroll
            for (int j = 0; j < 4; ++j)
                acc[i][j] = __builtin_amdgcn_mfma_f32_16x16x32_bf16(a[i], b[j], acc[i][j], 0, 0, 0);

        __syncthreads();   // drains this wave's gld_lds (vmcnt0) + lgkm; syncs
        cur ^= 1;
    }

    // Q pre-scale: 0.125 (1/sqrt(DK)) * log2(e), folded so attn uses raw exp2.
    const float emul = (mode == 0 && z == 0 && mode_override < 0) ? 0.18033688011112042f : 1.0f;

    #pragma unroll
    for (int i = 0; i < 4; ++i) {
        #pragma unroll
        for (int j = 0; j < 4; ++j) {
            const int gc  = col0 + wcol + j * 16 + l15;
            const float bv = bias[gc];
            const int gr0 = row0 + wrow + i * 16 + quad * 4;
            if (mode == 3) {
                float* df = (float*)dst;
                #pragma unroll
                for (int r = 0; r < 4; ++r)
                    df[(size_t)(gr0 + r) * 1024 + gc] = acc[i][j][r] + bv;
            } else if (mode == 2) {
                u16* dp = (u16*)dst;
                const int b = gr0 >> 11, s = gr0 & 2047;
                const int h = gc >> 6,  dk = gc & 63;
                u16x4 pk;
                pk[0] = f2bf(acc[i][j][0] + bv);
                pk[1] = f2bf(acc[i][j][1] + bv);
                pk[2] = f2bf(acc[i][j][2] + bv);
                pk[3] = f2bf(acc[i][j][3] + bv);
                *reinterpret_cast<u16x4*>(dp + ((size_t)((b * 16 + h) * 64 + dk)) * 2048 + s) = pk;
            } else {
                u16* dp = (u16*)dst;
                #pragma unroll
                for (int r = 0; r < 4; ++r) {
                    const int gr = gr0 + r;
                    const int b = gr >> 11, s = gr & 2047;
                    const int h = gc >> 6, dk = gc & 63;
                    dp[((size_t)((b * 16 + h) * 2048 + s)) * 64 + dk] = f2bf((acc[i][j][r] + bv) * emul);
                }
            }
        }
    }
}

// ---------------------------------------------------------------------------
// MFMA flash attention v3: 8 waves/block (512 thr), in-block K-split.
// Wave w = (qw = w&3, kh = w>>2): q rows q0+qw*32..+32, key half kh of each
// staged 64-key tile. 4096 total waves -> 4 waves/SIMD to hide the serial
// QK->exp->bpermute->PV chain. Double-buffered LDS: ONE barrier per iter;
// global loads issued at iter top, ds_write after compute (T14 async-stage).
// Partial accO/l combined once at the end via LDS (aliased onto the dead
// staging buffers). Softmax in-register via swapped QK^T (Z = K·Q^T),
// cvt_pk_bf16 + lane^32 ds_bpermute to build PV A-fragments; direct exp2
// (Q pre-scaled by 0.125*log2e in the projection GEMM).
// LDS chunk layout chunk(cb,r) -> cb*512 + (r^cb)*8 u16: conflict-free
// staging writes and fragment reads (verified 0 conflicts).
// ---------------------------------------------------------------------------
__global__ __launch_bounds__(512, 4) void attn_fused(
    const u16* __restrict__ Qb, const u16* __restrict__ Kb,
    const u16* __restrict__ Vt, const int* __restrict__ mask,
    u16* __restrict__ ctx)
{
    // 33 KB: double buffer 2 x (Ks 4096 + Vs 4096) u16 = 32 KB;
    // end-combine aliases the whole region as float[8448] = 33792 B.
    __shared__ __align__(16) u16 SMEM[16896];

    const int tid  = threadIdx.x;
    const int w    = tid >> 6;
    const int lane = tid & 63;
    const int l31  = lane & 31;
    const int hi   = lane >> 5;
    const int qw   = w & 3;
    const int kh   = w >> 2;

    // bijective XCD-contiguous swizzle: 512 blocks = 8 XCDs x 64
    const int id = blockIdx.x;
    const int sw = (id & 7) * 64 + (id >> 3);
    const int bh = sw >> 4;
    const int q0 = (sw & 15) * 128;
    const int b  = bh >> 4, h = bh & 15;

    const u16* Qp = Qb + (size_t)bh * 2048 * 64;
    const u16* Kp = Kb + (size_t)bh * 2048 * 64;
    const u16* Vp = Vt + (size_t)bh * 64 * 2048;
    const int* mp = mask + b * 2048;

    // Q fragments (B-operand): lane holds Q[q = q0+qw*32+l31][d = s*16+hi*8+j]
    bf16x8 qf[4];
    {
        const u16* qrow = Qp + (size_t)(q0 + qw * 32 + l31) * 64 + hi * 8;
        #pragma unroll
        for (int s = 0; s < 4; ++s)
            qf[s] = *reinterpret_cast<const bf16x8*>(qrow + s * 16);
    }

    // staging: 512 threads cover 512 16B chunks of K and of V^T per tile
    const int scb = tid & 7, sr = tid >> 3;          // sr in [0,64)
    const u16* kg0 = Kp + (size_t)sr * 64 + scb * 8;
    const u16* vg0 = Vp + (size_t)sr * 2048 + scb * 8;
    const int dK = scb * 512 + (sr ^ scb) * 8;       // chunk offset within a region

    // prologue: tile 0 -> buffer 0
    {
        u16x8 kr = *reinterpret_cast<const u16x8*>(kg0);
        u16x8 vr = *reinterpret_cast<const u16x8*>(vg0);
        *reinterpret_cast<u16x8*>(&SMEM[dK])        = kr;
        *reinterpret_cast<u16x8*>(&SMEM[4096 + dK]) = vr;
    }
    int mreg = mp[lane];
    __syncthreads();

    f32x16 accO0 = {}, accO1 = {};
    float la0 = 0.f, la1 = 0.f, la2 = 0.f, la3 = 0.f;
    const int paddr = (lane ^ 32) << 2;

    int cur = 0;
    for (int t = 0; t < 32; ++t) {
        const int kk = t * 64;
        // issue next-tile loads early (consumed by ds_write after compute)
        u16x8 krn, vrn; int mnext = 1;
        if (t < 31) {
            krn = *reinterpret_cast<const u16x8*>(kg0 + (size_t)(kk + 64) * 64);
            vrn = *reinterpret_cast<const u16x8*>(vg0 + (kk + 64));
            mnext = mp[kk + 64 + lane];
        }
        const u16* Kb_ = &SMEM[cur * 8192];
        const u16* Vb_ = &SMEM[cur * 8192 + 4096];

        const bool fullmask = (__ballot(mreg != 0) == ~0ull);

        // Z = K·Q^T over this wave's key half: Z[key rr][q = l31]
        f32x16 z = {};
        #pragma unroll
        for (int s = 0; s < 4; ++s) {
            const int cb = s * 2 + hi;
            const bf16x8 ak = *reinterpret_cast<const bf16x8*>(
                &Kb_[cb * 512 + (((kh * 32 + l31)) ^ cb) * 8]);
            z = __builtin_amdgcn_mfma_f32_32x32x16_bf16(ak, qf[s], z, 0, 0, 0);
        }
        float p[16];
        #pragma unroll
        for (int r = 0; r < 16; ++r) p[r] = exp2_hw(z[r]);
        if (!fullmask) {                   // rare general-mask path
            #pragma unroll
            for (int r = 0; r < 16; ++r) {
                const int kv = kk + kh * 32 + (r & 3) + 8 * (r >> 2) + 4 * hi;
                if (mp[kv] == 0) p[r] = 0.f;
            }
        }
        la0 += p[0] + p[4] + p[8]  + p[12];
        la1 += p[1] + p[5] + p[9]  + p[13];
        la2 += p[2] + p[6] + p[10] + p[14];
        la3 += p[3] + p[7] + p[11] + p[15];

        // pack P -> bf16 pairs (ascending key per hi-half)
        const uint32_t wd0 = cvt_pk_bf16(p[0],  p[1]);
        const uint32_t wd1 = cvt_pk_bf16(p[2],  p[3]);
        const uint32_t wd2 = cvt_pk_bf16(p[4],  p[5]);
        const uint32_t wd3 = cvt_pk_bf16(p[6],  p[7]);
        const uint32_t wd4 = cvt_pk_bf16(p[8],  p[9]);
        const uint32_t wd5 = cvt_pk_bf16(p[10], p[11]);
        const uint32_t wd6 = cvt_pk_bf16(p[12], p[13]);
        const uint32_t wd7 = cvt_pk_bf16(p[14], p[15]);
        // exchange with lane^32 to assemble A-fragments (k = hi*8+j)
        const uint32_t s0 = hi ? wd0 : wd2;
        const uint32_t s1 = hi ? wd1 : wd3;
        const uint32_t s2 = hi ? wd4 : wd6;
        const uint32_t s3 = hi ? wd5 : wd7;
        const uint32_t r0 = (uint32_t)__builtin_amdgcn_ds_bpermute(paddr, (int)s0);
        const uint32_t r1 = (uint32_t)__builtin_amdgcn_ds_bpermute(paddr, (int)s1);
        const uint32_t r2 = (uint32_t)__builtin_amdgcn_ds_bpermute(paddr, (int)s2);
        const uint32_t r3 = (uint32_t)__builtin_amdgcn_ds_bpermute(paddr, (int)s3);
        union { uint32_t u[4]; bf16x8 v; } A0, A1;
        A0.u[0] = hi ? r0  : wd0;
        A0.u[1] = hi ? r1  : wd1;
        A0.u[2] = hi ? wd2 : r0;
        A0.u[3] = hi ? wd3 : r1;
        A1.u[0] = hi ? r2  : wd4;
        A1.u[1] = hi ? r3  : wd5;
        A1.u[2] = hi ? wd6 : r2;
        A1.u[3] = hi ? wd7 : r3;

        // O += P V over this wave's key half
        const int ck0 = kh * 4 + hi;
        const int ck1 = kh * 4 + 2 + hi;
        const bf16x8 bv00 = *reinterpret_cast<const bf16x8*>(&Vb_[ck0 * 512 + ((     l31) ^ ck0) * 8]);
        const bf16x8 bv01 = *reinterpret_cast<const bf16x8*>(&Vb_[ck1 * 512 + ((     l31) ^ ck1) * 8]);
        const bf16x8 bv10 = *reinterpret_cast<const bf16x8*>(&Vb_[ck0 * 512 + ((32 + l31) ^ ck0) * 8]);
        const bf16x8 bv11 = *reinterpret_cast<const bf16x8*>(&Vb_[ck1 * 512 + ((32 + l31) ^ ck1) * 8]);
        accO0 = __builtin_amdgcn_mfma_f32_32x32x16_bf16(A0.v, bv00, accO0, 0, 0, 0);
        accO0 = __builtin_amdgcn_mfma_f32_32x32x16_bf16(A1.v, bv01, accO0, 0, 0, 0);
        accO1 = __builtin_amdgcn_mfma_f32_32x32x16_bf16(A0.v, bv10, accO1, 0, 0, 0);
        accO1 = __builtin_amdgcn_mfma_f32_32x32x16_bf16(A1.v, bv11, accO1, 0, 0, 0);

        // stage next tile into the other buffer (after this buffer's reads)
        if (t < 31) {
            const int nb = (cur ^ 1) * 8192;
            *reinterpret_cast<u16x8*>(&SMEM[nb + dK])        = krn;
            *reinterpret_cast<u16x8*>(&SMEM[nb + 4096 + dK]) = vrn;
        }
        __syncthreads();   // reads of buf[cur] done AND buf[cur^1] visible
        cur ^= 1;
        mreg = mnext;
    }

    // ---- combine kh halves (staging buffers dead; alias as float) ----
    // F: acc0 [0,4096), acc1 [4096,8192), l [8192,8320), inv [8320,8448)
    float l_part = (la0 + la1) + (la2 + la3);
    l_part += __shfl_xor(l_part, 32);      // this wave's full key-half sum, q=l31
    float* F = (float*)SMEM;
    if (kh) {
        #pragma unroll
        for (int r = 0; r < 16; ++r) F[qw * 1024 + r * 64 + lane] = accO0[r];
        #pragma unroll
        for (int r = 0; r < 16; ++r) F[4096 + qw * 1024 + r * 64 + lane] = accO1[r];
        if (lane < 32) F[8192 + qw * 32 + l31] = l_part;
    }
    __syncthreads();
    if (!kh && lane < 32)
        F[8320 + qw * 32 + l31] = 1.0f / (l_part + F[8192 + qw * 32 + l31]);
    __syncthreads();
    if (!kh) {
        #pragma unroll
        for (int r = 0; r < 16; ++r) {
            const int qr = (r & 3) + 8 * (r >> 2) + 4 * hi;
            const float iv = F[8320 + qw * 32 + qr];
            const float o0 = accO0[r] + F[qw * 1024 + r * 64 + lane];
            const float o1 = accO1[r] + F[4096 + qw * 1024 + r * 64 + lane];
            u16* row = ctx + (size_t)(b * 2048 + q0 + qw * 32 + qr) * 1024 + h * 64;
            row[l31]      = f2bf(o0 * iv);
            row[32 + l31] = f2bf(o1 * iv);
        }
    }
}

// ---------------------------------------------------------------------------
extern "C" void kernel_launch(void* const* d_in, const int* in_sizes, int n_in,
                              void* d_out, int out_size, void* d_ws, size_t ws_size,
                              hipStream_t stream) {
    const float* query = (const float*)d_in[0];
    const float* key   = (const float*)d_in[1];
    const float* value = (const float*)d_in[2];
    const int*   mask  = (const int*)d_in[3];
    const float* Wq = (const float*)d_in[4];
    const float* bq = (const float*)d_in[5];
    const float* Wk = (const float*)d_in[6];
    const float* bk = (const float*)d_in[7];
    const float* Wv = (const float*)d_in[8];
    const float* bv = (const float*)d_in[9];
    const float* Wo = (const float*)d_in[10];
    const float* bo = (const float*)d_in[11];
    float* out = (float*)d_out;

    u16* ws   = (u16*)d_ws;                  // offsets in u16 elems
    u16* Xq   = ws;                          // 4194304 each (8MB)
    u16* Xk   = ws + 4194304;
    u16* Xv   = ws + 8388608;
    u16* WqT  = ws + 12582912;               // 1048576 each (2MB)
    u16* WkT  = ws + 13631488;
    u16* WvT  = ws + 14680064;
    u16* WoT  = ws + 15728640;
    u16* Qb   = ws + 16777216;               // 8MB each
    u16* Kb   = ws + 20971520;
    u16* Vt   = ws + 25165824;               // high-water: 56MB
    u16* ctx  = Xq;                          // alias: Xq dead after proj GEMMs

    dim3 blk(256);
    cvt_all<<<dim3(1024, 1, 7), blk, 0, stream>>>(query, key, value, Wq, Wk, Wv, Wo,
                                                  Xq, Xk, Xv, WqT, WkT, WvT, WoT);
    gemm_bt<<<dim3(32, 8, 3),  blk, 0, stream>>>(Xq, Xk, Xv, WqT, WkT, WvT,
                                                 bq, bk, bv, Qb, Kb, Vt, -1);
    attn_fused<<<dim3(512), dim3(512), 0, stream>>>(Qb, Kb, Vt, mask, ctx);
    gemm_bt<<<dim3(32, 8, 1),  blk, 0, stream>>>(ctx, ctx, ctx, WoT, WoT, WoT,
                                                 bo, bo, bo, out, out, out, 3);
}